// Round 16
// baseline (342.298 us; speedup 1.0000x reference)
//
#include <hip/hip_runtime.h>
#include <hip/hip_fp16.h>
#include <math.h>

#define HW 512
#define MASK 511
#define IMG (512*512)
#define NSTEP 16
#define NSLICE 17

#define TR 84             // tile rows: [Y0-10, Y0+74)
#define TSTR 104          // ushort stride/row: 13 granules (odd, coprime 32 -> 2-way max)
#define WSB_OFF 32        // ushort offset of B-frag table in ws

typedef _Float16 half_t;
typedef __attribute__((ext_vector_type(8))) _Float16 f16x8;
typedef __attribute__((ext_vector_type(16))) float f32x16;

#define SBAR() __builtin_amdgcn_sched_barrier(0)

// B-frags (Toeplitz, 32x32x16): frag f = dy*8 + c*2 + s  (c: k-chunk, s: hi/lo).
// lane l, elem j -> k = 8*(l>>5)+j, n = l&31.
// Window base = out-col-base - 16; input i = 16c + k; tap = i - n - 6.
// B[k][n] = W_s[dy][16c + k - n - 6] when 0 <= idx <= 20, else 0.
// A uses the same (lane,j)->k map => any fixed HW k-permutation cancels.
__global__ void prep_kernel(const float* __restrict__ w1,
                            const float* __restrict__ w2,
                            const float* __restrict__ w3,
                            float* __restrict__ ws) {
    int tid = threadIdx.x;
    if (tid == 0) {
        // 1->10->1 MLP on nonneg scalar collapses: C = sum_o w3[o]*max(w2[o],0)
        float c = 0.f;
        for (int o = 0; o < 10; ++o) c += w3[o] * fmaxf(w2[o], 0.f);
        ws[0] = c;
    }
    half_t* wsb = (half_t*)((unsigned short*)ws + WSB_OFF);
    for (int u = tid; u < 21 * 8 * 512; u += blockDim.x) {
        int f = u >> 9, rem = u & 511, l = rem >> 3, j = rem & 7;
        int dy = f >> 3, c = (f >> 1) & 3, s = f & 1;
        int k = ((l >> 5) << 3) + j, n = l & 31;
        int idx = 16 * c + k - n - 6;
        float wf = (idx >= 0 && idx <= 20) ? w1[dy * 21 + idx] : 0.f;
        half_t h = (half_t)wf;
        wsb[u] = (s == 0) ? h : (half_t)(wf - (float)h);   // W = W_h + W_l
    }
}

__global__ void copy_kernel(const float* __restrict__ x, float* __restrict__ out) {
    int i = blockIdx.x * blockDim.x + threadIdx.x;   // float4 index
    if (i < 8 * 65536) {
        const float4* in4 = (const float4*)x;
        float4* out4 = (float4*)out;
        int b = i >> 16;
        int off = i & 65535;
        out4[(size_t)b * (NSLICE * 65536) + off] = in4[i];
    }
}

__global__ __launch_bounds__(256, 2)
void step_kernel(const float* __restrict__ state_base,
                 float* __restrict__ out_base,
                 const float* __restrict__ ws,
                 int t) {
    __shared__ half_t tlh[TR * TSTR];   // x fp16 tile, 17472 B

    const int tid = threadIdx.x;
    const int lane = tid & 63, w = tid >> 6;          // 4 waves: (wr,wc) 2x2
    const int wr = w >> 1, wc = w & 1;
    const int X0 = blockIdx.x * 64, Y0 = blockIdx.y * 64, b = blockIdx.z;

    const float* __restrict__ in  = state_base + (size_t)(b * NSLICE + (t - 1)) * IMG;
    float* __restrict__ outp      = out_base   + (size_t)(b * NSLICE + t) * IMG;

    // stage 84 x 96 fp32 -> fp16 tile; cols gx in [X0-16, X0+80)
    for (int u = tid; u < TR * 12; u += 256) {
        int r = u / 12, ch = u - r * 12;
        int gr = (Y0 + r - 10) & MASK;
        int gc = X0 + 8 * ch - 16;
        float4 a  = *(const float4*)&in[gr * HW + (gc & MASK)];
        float4 c2 = *(const float4*)&in[gr * HW + ((gc + 4) & MASK)];
        float v[8] = {a.x, a.y, a.z, a.w, c2.x, c2.y, c2.z, c2.w};
        f16x8 hh;
        #pragma unroll
        for (int q = 0; q < 8; ++q) hh[q] = (half_t)v[q];
        *(f16x8*)&tlh[r * TSTR + 8 * ch] = hh;
    }

    // prefetch fp32 residual centers (L2-hot) while staging drains.
    // D map (m74/m101): lane l, reg q -> row = (q&3)+8*(q>>2)+4*(l>>5), col = l&31
    const int gxc = X0 + 32 * wc + (lane & 31);
    const int gyb = Y0 + 32 * wr + ((lane >> 5) << 2);
    float xv[16];
    #pragma unroll
    for (int q = 0; q < 16; ++q)
        xv[q] = in[(gyb + (q & 3) + ((q >> 2) << 3)) * HW + gxc];

    __syncthreads();

    const f16x8* bglob = (const f16x8*)((const unsigned short*)ws + WSB_OFF);
    const int rowoff = (32 * wr + (lane & 31)) * TSTR + 32 * wc + ((lane >> 5) << 3);

    f32x16 acc = {0.f,0.f,0.f,0.f,0.f,0.f,0.f,0.f,0.f,0.f,0.f,0.f,0.f,0.f,0.f,0.f};

    // double-buffered A-frags (4 each) and B-sets (8 each), all named regs
    f16x8 a0,a1,a2,a3, c0,c1,c2,c3;
    f16x8 b0,b1,b2,b3,b4,b5,b6,b7;     // B set 0: (c,s) = (0,h)(0,l)(1,h)...(3,l)
    f16x8 d0,d1,d2,d3,d4,d5,d6,d7;     // B set 1

    auto LOADA = [&](f16x8& A0, f16x8& A1, f16x8& A2, f16x8& A3, int dy) {
        const half_t* rp = &tlh[rowoff + dy * TSTR];
        A0 = *(const f16x8*)(rp);      A1 = *(const f16x8*)(rp + 16);
        A2 = *(const f16x8*)(rp + 32); A3 = *(const f16x8*)(rp + 48);
    };
    auto LOADB = [&](f16x8& B0, f16x8& B1, f16x8& B2, f16x8& B3,
                     f16x8& B4, f16x8& B5, f16x8& B6, f16x8& B7, int dy) {
        const f16x8* nb = bglob + dy * 512 + lane;   // frag stride 64 lanes
        B0 = nb[0];   B1 = nb[64];  B2 = nb[128]; B3 = nb[192];
        B4 = nb[256]; B5 = nb[320]; B6 = nb[384]; B7 = nb[448];
    };
    auto MFMA8 = [&](const f16x8& A0, const f16x8& A1, const f16x8& A2,
                     const f16x8& A3,
                     const f16x8& B0, const f16x8& B1, const f16x8& B2,
                     const f16x8& B3, const f16x8& B4, const f16x8& B5,
                     const f16x8& B6, const f16x8& B7) {
        acc = __builtin_amdgcn_mfma_f32_32x32x16_f16(A0, B0, acc, 0,0,0);  // c0 h
        acc = __builtin_amdgcn_mfma_f32_32x32x16_f16(A1, B2, acc, 0,0,0);  // c1 h
        acc = __builtin_amdgcn_mfma_f32_32x32x16_f16(A2, B4, acc, 0,0,0);  // c2 h
        acc = __builtin_amdgcn_mfma_f32_32x32x16_f16(A3, B6, acc, 0,0,0);  // c3 h
        acc = __builtin_amdgcn_mfma_f32_32x32x16_f16(A0, B1, acc, 0,0,0);  // c0 l
        acc = __builtin_amdgcn_mfma_f32_32x32x16_f16(A1, B3, acc, 0,0,0);  // c1 l
        acc = __builtin_amdgcn_mfma_f32_32x32x16_f16(A2, B5, acc, 0,0,0);  // c2 l
        acc = __builtin_amdgcn_mfma_f32_32x32x16_f16(A3, B7, acc, 0,0,0);  // c3 l
    };

    // prologue: dy=0 operands + dy=1 B-set
    LOADA(a0,a1,a2,a3, 0);
    LOADB(b0,b1,b2,b3,b4,b5,b6,b7, 0);
    LOADB(d0,d1,d2,d3,d4,d5,d6,d7, 1);

    #pragma unroll 1
    for (int k = 0; k < 10; ++k) {
        const int dy1 = 2*k + 1;
        LOADA(c0,c1,c2,c3, dy1);
        SBAR();
        MFMA8(a0,a1,a2,a3, b0,b1,b2,b3,b4,b5,b6,b7);
        SBAR();
        LOADB(b0,b1,b2,b3,b4,b5,b6,b7, dy1 + 1);
        LOADA(a0,a1,a2,a3, dy1 + 1);
        SBAR();
        MFMA8(c0,c1,c2,c3, d0,d1,d2,d3,d4,d5,d6,d7);
        SBAR();
        if (k < 9) LOADB(d0,d1,d2,d3,d4,d5,d6,d7, dy1 + 2);
    }
    MFMA8(a0,a1,a2,a3, b0,b1,b2,b3,b4,b5,b6,b7);         // dy = 20

    const float C = ws[0];
    #pragma unroll
    for (int q = 0; q < 16; ++q) {
        int gy = gyb + (q & 3) + ((q >> 2) << 3);
        float a  = xv[q] + C * fmaxf(acc[q], 0.f);
        float e  = __expf(2.f * fabsf(a));        // tanh(|a|) = 1 - 2/(e+1)
        float r  = 1.f - 2.f * __builtin_amdgcn_rcpf(e + 1.f);
        outp[gy * HW + gxc] = copysignf(r, a);
    }
}

extern "C" void kernel_launch(void* const* d_in, const int* in_sizes, int n_in,
                              void* d_out, int out_size, void* d_ws, size_t ws_size,
                              hipStream_t stream) {
    const float* x  = (const float*)d_in[0];
    const float* w1 = (const float*)d_in[1];
    const float* w2 = (const float*)d_in[2];
    const float* w3 = (const float*)d_in[3];
    float* out = (float*)d_out;
    float* ws  = (float*)d_ws;

    prep_kernel<<<1, 256, 0, stream>>>(w1, w2, w3, ws);
    copy_kernel<<<2048, 256, 0, stream>>>(x, out);

    dim3 grid(8, 8, 8);      // 512 blocks (64x64 out each) = 2/CU
    dim3 block(256);
    for (int t = 1; t <= NSTEP; ++t)
        step_kernel<<<grid, block, 0, stream>>>(out, out, ws, t);
}

// Round 17
// 253.991 us; speedup vs baseline: 1.3477x; 1.3477x over previous
//
#include <hip/hip_runtime.h>
#include <hip/hip_fp16.h>
#include <math.h>

#define HW 512
#define MASK 511
#define IMG (512*512)
#define NSTEP 16
#define NSLICE 17

#define TR 84             // tile rows: [Y0-10, Y0+74)
#define TSTR 168          // halfs/row: 21 granules (odd, coprime 32 -> conflict-free)
#define WSB_OFF 32        // ushort offset of B-frag table in ws

typedef _Float16 half_t;
typedef __attribute__((ext_vector_type(8))) _Float16 f16x8;
typedef __attribute__((ext_vector_type(4))) float f32x4;

#define SBAR() __builtin_amdgcn_sched_barrier(0)

// B-frags (Toeplitz, 16x16x32): frag f2 = dy*4 + v*2 + s  (identical to R13/R15).
// lane l, elem j -> k = 8*(l>>4)+j, n = l&15, d = k-n.
// v=0: B[k][n] = W[dy][d-6]  for d in [6,15]  (dx 0..9,  A-window 16j)
// v=1: B[k][n] = W[dy][d+10] for d in [0,10]  (dx 10..20, A-window 16j+16)
// W = W_h + W_l (fp16 split); x single fp16; A shares the (lane,j)->k map.
__global__ void prep_kernel(const float* __restrict__ w1,
                            const float* __restrict__ w2,
                            const float* __restrict__ w3,
                            float* __restrict__ ws) {
    int tid = threadIdx.x;
    if (tid == 0) {
        // 1->10->1 MLP on nonneg scalar collapses: C = sum_o w3[o]*max(w2[o],0)
        float c = 0.f;
        for (int o = 0; o < 10; ++o) c += w3[o] * fmaxf(w2[o], 0.f);
        ws[0] = c;
    }
    half_t* wsb = (half_t*)((unsigned short*)ws + WSB_OFF);
    for (int u = tid; u < 84 * 512; u += blockDim.x) {
        int f2 = u >> 9, rem = u & 511, l = rem >> 3, j = rem & 7;
        int dy = f2 >> 2, v = (f2 >> 1) & 1, s = f2 & 1;
        int k = ((l >> 4) << 3) + j, n = l & 15, d = k - n;
        float wf = 0.f;
        if (v == 0) { if (d >= 6 && d <= 15) wf = w1[dy * 21 + d - 6]; }
        else        { if (d >= 0 && d <= 10) wf = w1[dy * 21 + d + 10]; }
        half_t h = (half_t)wf;
        wsb[u] = (s == 0) ? h : (half_t)(wf - (float)h);   // W = W_h + W_l
    }
}

__global__ void copy_kernel(const float* __restrict__ x, float* __restrict__ out) {
    int i = blockIdx.x * blockDim.x + threadIdx.x;   // float4 index
    if (i < 8 * 65536) {
        const float4* in4 = (const float4*)x;
        float4* out4 = (float4*)out;
        int b = i >> 16;
        int off = i & 65535;
        out4[(size_t)b * (NSLICE * 65536) + off] = in4[i];
    }
}

__global__ __launch_bounds__(256, 1)
void step_kernel(const float* __restrict__ state_base,
                 float* __restrict__ out_base,
                 const float* __restrict__ ws,
                 int t) {
    __shared__ half_t tlh[TR * TSTR];   // 28224 B

    const int tid = threadIdx.x;
    const int lane = tid & 63, w = tid >> 6;          // 4 waves, 16 rows x 128 cols each
    const int X0 = blockIdx.x * 128, Y0 = blockIdx.y * 64, b = blockIdx.z;

    const float* __restrict__ in  = state_base + (size_t)(b * NSLICE + (t - 1)) * IMG;
    float* __restrict__ outp      = out_base   + (size_t)(b * NSLICE + t) * IMG;

    // stage 84 x 160 fp32 -> fp16 tile; cols gx in [X0-16, X0+144)
    for (int u = tid; u < TR * 20; u += 256) {
        int r = u / 20, ch = u - r * 20;
        int gr = (Y0 + r - 10) & MASK;
        int gc = X0 + 8 * ch - 16;
        float4 a  = *(const float4*)&in[gr * HW + (gc & MASK)];
        float4 c2 = *(const float4*)&in[gr * HW + ((gc + 4) & MASK)];
        float v[8] = {a.x, a.y, a.z, a.w, c2.x, c2.y, c2.z, c2.w};
        f16x8 hh;
        #pragma unroll
        for (int q = 0; q < 8; ++q) hh[q] = (half_t)v[q];
        *(f16x8*)&tlh[r * TSTR + 8 * ch] = hh;
    }

    // prefetch fp32 residual centers (L2-hot) while staging drains.
    // D map: lane l, reg q -> row = (l>>4)*4 + q, col = l&15 (16x16, dtype-indep)
    const int gy0 = Y0 + 16 * w + ((lane >> 4) << 2);
    const int gxb = X0 + (lane & 15);
    float xvf[32];
    #pragma unroll
    for (int j = 0; j < 8; ++j)
        #pragma unroll
        for (int q = 0; q < 4; ++q)
            xvf[j * 4 + q] = in[(gy0 + q) * HW + gxb + 16 * j];

    __syncthreads();

    const f16x8* bglob = (const f16x8*)((const unsigned short*)ws + WSB_OFF);
    const int rowoff = (16 * w + (lane & 15)) * TSTR + ((lane >> 4) << 3);

    f32x4 acc[8];
    #pragma unroll
    for (int j = 0; j < 8; ++j) acc[j] = (f32x4){0.f, 0.f, 0.f, 0.f};

    // double-buffered A (9 frags: windows 16j, j=0..8) and B (4 frags), static idx
    f16x8 aX[9], aY[9];
    f16x8 bX[4], bY[4];     // [0]=h0 [1]=l0 [2]=h1 [3]=l1

    auto LOADA = [&](f16x8 (&A)[9], int dy) {
        const half_t* rp = &tlh[rowoff + dy * TSTR];
        #pragma unroll
        for (int i = 0; i < 9; ++i) A[i] = *(const f16x8*)(rp + 16 * i);
    };
    auto LOADB = [&](f16x8 (&B)[4], int dy) {
        const f16x8* nb = bglob + dy * 256 + lane;
        B[0] = nb[0]; B[1] = nb[64]; B[2] = nb[128]; B[3] = nb[192];
    };
    // per col-group j: v0 uses A[j], v1 uses A[j+1]; order matches R15 exactly
    auto MFMA32 = [&](const f16x8 (&A)[9], const f16x8 (&B)[4]) {
        #pragma unroll
        for (int j = 0; j < 8; ++j)
            acc[j] = __builtin_amdgcn_mfma_f32_16x16x32_f16(A[j],   B[0], acc[j], 0,0,0);
        #pragma unroll
        for (int j = 0; j < 8; ++j)
            acc[j] = __builtin_amdgcn_mfma_f32_16x16x32_f16(A[j+1], B[2], acc[j], 0,0,0);
        #pragma unroll
        for (int j = 0; j < 8; ++j)
            acc[j] = __builtin_amdgcn_mfma_f32_16x16x32_f16(A[j],   B[1], acc[j], 0,0,0);
        #pragma unroll
        for (int j = 0; j < 8; ++j)
            acc[j] = __builtin_amdgcn_mfma_f32_16x16x32_f16(A[j+1], B[3], acc[j], 0,0,0);
    };

    // prologue: dy=0 operands + dy=1 B-set
    LOADA(aX, 0);
    LOADB(bX, 0);
    LOADB(bY, 1);

    #pragma unroll 1
    for (int k = 0; k < 10; ++k) {
        const int dy1 = 2 * k + 1;
        LOADA(aY, dy1);
        SBAR();
        MFMA32(aX, bX);
        SBAR();
        LOADB(bX, dy1 + 1);
        LOADA(aX, dy1 + 1);
        SBAR();
        MFMA32(aY, bY);
        SBAR();
        if (k < 9) LOADB(bY, dy1 + 2);
    }
    MFMA32(aX, bX);                                      // dy = 20

    const float C = ws[0];
    #pragma unroll
    for (int j = 0; j < 8; ++j) {
        int gx = gxb + 16 * j;
        #pragma unroll
        for (int q = 0; q < 4; ++q) {
            int gy = gy0 + q;
            float a  = xvf[j * 4 + q] + C * fmaxf(acc[j][q], 0.f);
            float e  = __expf(2.f * fabsf(a));        // tanh(|a|) = 1 - 2/(e+1)
            float r  = 1.f - 2.f * __builtin_amdgcn_rcpf(e + 1.f);
            outp[gy * HW + gx] = copysignf(r, a);
        }
    }
}

extern "C" void kernel_launch(void* const* d_in, const int* in_sizes, int n_in,
                              void* d_out, int out_size, void* d_ws, size_t ws_size,
                              hipStream_t stream) {
    const float* x  = (const float*)d_in[0];
    const float* w1 = (const float*)d_in[1];
    const float* w2 = (const float*)d_in[2];
    const float* w3 = (const float*)d_in[3];
    float* out = (float*)d_out;
    float* ws  = (float*)d_ws;

    prep_kernel<<<1, 256, 0, stream>>>(w1, w2, w3, ws);
    copy_kernel<<<2048, 256, 0, stream>>>(x, out);

    dim3 grid(4, 8, 8);      // 256 blocks (64x128 out each) = 1/CU
    dim3 block(256);
    for (int t = 1; t <= NSTEP; ++t)
        step_kernel<<<grid, block, 0, stream>>>(out, out, ws, t);
}

// Round 18
// 241.606 us; speedup vs baseline: 1.4168x; 1.0513x over previous
//
#include <hip/hip_runtime.h>
#include <hip/hip_fp16.h>
#include <math.h>

#define HW 512
#define MASK 511
#define IMG (512*512)
#define NSTEP 16
#define NSLICE 17

#define TR 84             // tile rows: [Y0-10, Y0+74)
#define TSTR 104          // ushort stride/row: 13 granules (odd -> uniform banks)
#define WSB_OFF 32        // ushort offset of B-frag table in ws

typedef _Float16 half_t;
typedef __attribute__((ext_vector_type(8))) _Float16 f16x8;
typedef __attribute__((ext_vector_type(4))) float f32x4;

#define SBAR() __builtin_amdgcn_sched_barrier(0)

// B-frags (Toeplitz, 16x16x32): frag f2 = dy*4 + v*2 + s  (v: dx-window, s: hi/lo).
// lane l, elem j -> k = 8*(l>>4)+j, n = l&15, d = k-n.
// v=0: B[k][n] = W[dy][d-6]  for d in [6,15]  (dx 0..9,  A-window 16j)
// v=1: B[k][n] = W[dy][d+10] for d in [0,10]  (dx 10..20, A-window 16j+16)
// W = W_h + W_l (fp16 split) => W effectively exact; x is single fp16 (2-pass).
__global__ void prep_kernel(const float* __restrict__ w1,
                            const float* __restrict__ w2,
                            const float* __restrict__ w3,
                            float* __restrict__ ws) {
    int tid = threadIdx.x;
    if (tid == 0) {
        // 1->10->1 MLP on nonneg scalar collapses: C = sum_o w3[o]*max(w2[o],0)
        float c = 0.f;
        for (int o = 0; o < 10; ++o) c += w3[o] * fmaxf(w2[o], 0.f);
        ws[0] = c;
    }
    half_t* wsb = (half_t*)((unsigned short*)ws + WSB_OFF);
    for (int u = tid; u < 84 * 512; u += blockDim.x) {
        int f2 = u >> 9, rem = u & 511, l = rem >> 3, j = rem & 7;
        int dy = f2 >> 2, v = (f2 >> 1) & 1, s = f2 & 1;
        int k = ((l >> 4) << 3) + j, n = l & 15, d = k - n;
        float wf = 0.f;
        if (v == 0) { if (d >= 6 && d <= 15) wf = w1[dy * 21 + d - 6]; }
        else        { if (d >= 0 && d <= 10) wf = w1[dy * 21 + d + 10]; }
        half_t h = (half_t)wf;
        wsb[u] = (s == 0) ? h : (half_t)(wf - (float)h);   // W = W_h + W_l
    }
}

__global__ void copy_kernel(const float* __restrict__ x, float* __restrict__ out) {
    int i = blockIdx.x * blockDim.x + threadIdx.x;   // float4 index
    if (i < 8 * 65536) {
        const float4* in4 = (const float4*)x;
        float4* out4 = (float4*)out;
        int b = i >> 16;
        int off = i & 65535;
        out4[(size_t)b * (NSLICE * 65536) + off] = in4[i];
    }
}

__global__ __launch_bounds__(256, 2)
void step_kernel(const float* __restrict__ state_base,
                 float* __restrict__ out_base,
                 const float* __restrict__ ws,
                 int t) {
    __shared__ half_t tlh[TR * TSTR];   // x fp16 tile, 17472 B

    const int tid = threadIdx.x;
    const int lane = tid & 63, w = tid >> 6;          // 4 waves, 16x64 out each
    const int X0 = blockIdx.x * 64, Y0 = blockIdx.y * 64, b = blockIdx.z;

    const float* __restrict__ in  = state_base + (size_t)(b * NSLICE + (t - 1)) * IMG;
    float* __restrict__ outp      = out_base   + (size_t)(b * NSLICE + t) * IMG;

    // stage 84 x 96 fp32 -> fp16 tile; cols gx in [X0-16, X0+80)
    for (int u = tid; u < TR * 12; u += 256) {
        int r = u / 12, ch = u - r * 12;
        int gr = (Y0 + r - 10) & MASK;
        int gc = X0 + 8 * ch - 16;
        float4 a  = *(const float4*)&in[gr * HW + (gc & MASK)];
        float4 c2 = *(const float4*)&in[gr * HW + ((gc + 4) & MASK)];
        float v[8] = {a.x, a.y, a.z, a.w, c2.x, c2.y, c2.z, c2.w};
        f16x8 hh;
        #pragma unroll
        for (int q = 0; q < 8; ++q) hh[q] = (half_t)v[q];
        *(f16x8*)&tlh[r * TSTR + 8 * ch] = hh;
    }

    // prefetch fp32 residual centers (L2-hot) while staging drains
    const int gy0 = Y0 + 16 * w + (((lane >> 4) & 3) << 2);
    const int gxb = X0 + (lane & 15);
    float4 xv0, xv1, xv2, xv3;
    xv0.x = in[(gy0+0)*HW + gxb];      xv0.y = in[(gy0+1)*HW + gxb];
    xv0.z = in[(gy0+2)*HW + gxb];      xv0.w = in[(gy0+3)*HW + gxb];
    xv1.x = in[(gy0+0)*HW + gxb+16];   xv1.y = in[(gy0+1)*HW + gxb+16];
    xv1.z = in[(gy0+2)*HW + gxb+16];   xv1.w = in[(gy0+3)*HW + gxb+16];
    xv2.x = in[(gy0+0)*HW + gxb+32];   xv2.y = in[(gy0+1)*HW + gxb+32];
    xv2.z = in[(gy0+2)*HW + gxb+32];   xv2.w = in[(gy0+3)*HW + gxb+32];
    xv3.x = in[(gy0+0)*HW + gxb+48];   xv3.y = in[(gy0+1)*HW + gxb+48];
    xv3.z = in[(gy0+2)*HW + gxb+48];   xv3.w = in[(gy0+3)*HW + gxb+48];

    __syncthreads();

    const f16x8* bglob = (const f16x8*)((const unsigned short*)ws + WSB_OFF);
    const int rowoff = (16 * w + (lane & 15)) * TSTR + ((lane >> 4) << 3);

    f32x4 acc0 = {0.f,0.f,0.f,0.f}, acc1 = acc0, acc2 = acc0, acc3 = acc0;

    // A double-buffer + B TRIPLE-buffer (3-dy prefetch > L2 latency; B table
    // is 86KB > 32KB L1, so every LOADB is an L2 access ~200 cyc).
    f16x8 aX[5], aY[5];
    f16x8 bA[4], bB[4], bC[4];     // [0]=h0 [1]=l0 [2]=h1 [3]=l1

    auto LOADA = [&](f16x8 (&A)[5], int dy) {
        const half_t* rp = &tlh[rowoff + dy * TSTR];
        #pragma unroll
        for (int i = 0; i < 5; ++i) A[i] = *(const f16x8*)(rp + 16 * i);
    };
    auto LOADB = [&](f16x8 (&B)[4], int dy) {
        const f16x8* nb = bglob + dy * 256 + lane;
        B[0] = nb[0]; B[1] = nb[64]; B[2] = nb[128]; B[3] = nb[192];
    };
    auto MFMA16 = [&](const f16x8 (&A)[5], const f16x8 (&B)[4]) {
        acc0 = __builtin_amdgcn_mfma_f32_16x16x32_f16(A[0], B[0], acc0, 0,0,0);
        acc1 = __builtin_amdgcn_mfma_f32_16x16x32_f16(A[1], B[0], acc1, 0,0,0);
        acc2 = __builtin_amdgcn_mfma_f32_16x16x32_f16(A[2], B[0], acc2, 0,0,0);
        acc3 = __builtin_amdgcn_mfma_f32_16x16x32_f16(A[3], B[0], acc3, 0,0,0);
        acc0 = __builtin_amdgcn_mfma_f32_16x16x32_f16(A[1], B[2], acc0, 0,0,0);
        acc1 = __builtin_amdgcn_mfma_f32_16x16x32_f16(A[2], B[2], acc1, 0,0,0);
        acc2 = __builtin_amdgcn_mfma_f32_16x16x32_f16(A[3], B[2], acc2, 0,0,0);
        acc3 = __builtin_amdgcn_mfma_f32_16x16x32_f16(A[4], B[2], acc3, 0,0,0);
        acc0 = __builtin_amdgcn_mfma_f32_16x16x32_f16(A[0], B[1], acc0, 0,0,0);
        acc1 = __builtin_amdgcn_mfma_f32_16x16x32_f16(A[1], B[1], acc1, 0,0,0);
        acc2 = __builtin_amdgcn_mfma_f32_16x16x32_f16(A[2], B[1], acc2, 0,0,0);
        acc3 = __builtin_amdgcn_mfma_f32_16x16x32_f16(A[3], B[1], acc3, 0,0,0);
        acc0 = __builtin_amdgcn_mfma_f32_16x16x32_f16(A[1], B[3], acc0, 0,0,0);
        acc1 = __builtin_amdgcn_mfma_f32_16x16x32_f16(A[2], B[3], acc1, 0,0,0);
        acc2 = __builtin_amdgcn_mfma_f32_16x16x32_f16(A[3], B[3], acc2, 0,0,0);
        acc3 = __builtin_amdgcn_mfma_f32_16x16x32_f16(A[4], B[3], acc3, 0,0,0);
    };

    // prologue: A(0) + B(0),B(1),B(2) in flight
    LOADA(aX, 0);
    LOADB(bA, 0); LOADB(bB, 1); LOADB(bC, 2);

    // fully-unrolled 21-stage pipeline; BT is freed by MFMA then reloads dy+3
    #define ST(dy, AT, AN, BT)                                  \
        do {                                                    \
            if ((dy) < 20) LOADA(AN, (dy) + 1);                 \
            SBAR();                                             \
            MFMA16(AT, BT);                                     \
            SBAR();                                             \
            if ((dy) + 3 < 21) LOADB(BT, (dy) + 3);             \
        } while (0)

    ST( 0, aX, aY, bA); ST( 1, aY, aX, bB); ST( 2, aX, aY, bC);
    ST( 3, aY, aX, bA); ST( 4, aX, aY, bB); ST( 5, aY, aX, bC);
    ST( 6, aX, aY, bA); ST( 7, aY, aX, bB); ST( 8, aX, aY, bC);
    ST( 9, aY, aX, bA); ST(10, aX, aY, bB); ST(11, aY, aX, bC);
    ST(12, aX, aY, bA); ST(13, aY, aX, bB); ST(14, aX, aY, bC);
    ST(15, aY, aX, bA); ST(16, aX, aY, bB); ST(17, aY, aX, bC);
    ST(18, aX, aY, bA); ST(19, aY, aX, bB); ST(20, aX, aY, bC);
    #undef ST

    // D layout: lane l, reg q -> row = (l>>4)*4 + q, col = l&15 (dtype-indep)
    const float C = ws[0];
    auto EPI = [&](const f32x4& a4v, const float4& xv, int j) {
        int gx = gxb + 16 * j;
        float cv[4] = {xv.x, xv.y, xv.z, xv.w};
        #pragma unroll
        for (int q = 0; q < 4; ++q) {
            int gy = gy0 + q;
            float a  = cv[q] + C * fmaxf(a4v[q], 0.f);
            float e  = __expf(2.f * fabsf(a));        // tanh(|a|) = 1 - 2/(e+1)
            float r  = 1.f - 2.f * __builtin_amdgcn_rcpf(e + 1.f);
            outp[gy * HW + gx] = copysignf(r, a);
        }
    };
    EPI(acc0, xv0, 0); EPI(acc1, xv1, 1); EPI(acc2, xv2, 2); EPI(acc3, xv3, 3);
}

extern "C" void kernel_launch(void* const* d_in, const int* in_sizes, int n_in,
                              void* d_out, int out_size, void* d_ws, size_t ws_size,
                              hipStream_t stream) {
    const float* x  = (const float*)d_in[0];
    const float* w1 = (const float*)d_in[1];
    const float* w2 = (const float*)d_in[2];
    const float* w3 = (const float*)d_in[3];
    float* out = (float*)d_out;
    float* ws  = (float*)d_ws;

    prep_kernel<<<1, 256, 0, stream>>>(w1, w2, w3, ws);
    copy_kernel<<<2048, 256, 0, stream>>>(x, out);

    dim3 grid(8, 8, 8);      // 512 blocks (64x64 out each) = 2/CU
    dim3 block(256);
    for (int t = 1; t <= NSTEP; ++t)
        step_kernel<<<grid, block, 0, stream>>>(out, out, ws, t);
}

// Round 19
// 211.341 us; speedup vs baseline: 1.6196x; 1.1432x over previous
//
#include <hip/hip_runtime.h>
#include <hip/hip_fp16.h>
#include <math.h>

#define HW 512
#define MASK 511
#define IMG (512*512)
#define NSTEP 16
#define NSLICE 17

#define TR 85             // tile rows: [Y0-10, Y0+75); row 84 only feeds zero-weights
#define TSTR 104          // ushort stride/row: 13 granules (odd -> uniform banks)
#define WSB_OFF 32        // ushort offset of B-frag table in ws

typedef _Float16 half_t;
typedef __attribute__((ext_vector_type(8))) _Float16 f16x8;
typedef __attribute__((ext_vector_type(4))) float f32x4;

#define SBAR() __builtin_amdgcn_sched_barrier(0)

// B-frags (2-row Toeplitz, 16x16x32): frag f = p*6 + u*2 + s.
//   p: dy-pair (rows 2p, 2p+1), u: window class (r = 16u), s: W_h/W_l split.
// lane l, elem j -> k = 8*(l>>4)+j, n = l&15.
//   k<16  -> dy = 2p,   tap d = 16u + k      - n - 6
//   k>=16 -> dy = 2p+1, tap d = 16u + (k-16) - n - 6
// B = W_s[dy][d] if dy<=20 && 0<=d<=20 else 0.  A shares the (lane,j)->k map,
// so any fixed HW k-permutation cancels in the contraction.
__global__ void prep_kernel(const float* __restrict__ w1,
                            const float* __restrict__ w2,
                            const float* __restrict__ w3,
                            float* __restrict__ ws) {
    int tid = threadIdx.x;
    if (tid == 0) {
        // 1->10->1 MLP on nonneg scalar collapses: C = sum_o w3[o]*max(w2[o],0)
        float c = 0.f;
        for (int o = 0; o < 10; ++o) c += w3[o] * fmaxf(w2[o], 0.f);
        ws[0] = c;
    }
    half_t* wsb = (half_t*)((unsigned short*)ws + WSB_OFF);
    for (int u2 = tid; u2 < 66 * 512; u2 += blockDim.x) {
        int f = u2 >> 9, rem = u2 & 511, l = rem >> 3, j = rem & 7;
        int p = f / 6, rc = (f % 6) >> 1, s = f & 1;
        int k = ((l >> 4) << 3) + j, n = l & 15;
        int dy = 2 * p + (k >= 16 ? 1 : 0);
        int d = 16 * rc + (k & 15) - n - 6;
        float wf = (dy <= 20 && d >= 0 && d <= 20) ? w1[dy * 21 + d] : 0.f;
        half_t h = (half_t)wf;
        wsb[u2] = (s == 0) ? h : (half_t)(wf - (float)h);   // W = W_h + W_l
    }
}

__global__ void copy_kernel(const float* __restrict__ x, float* __restrict__ out) {
    int i = blockIdx.x * blockDim.x + threadIdx.x;   // float4 index
    if (i < 8 * 65536) {
        const float4* in4 = (const float4*)x;
        float4* out4 = (float4*)out;
        int b = i >> 16;
        int off = i & 65535;
        out4[(size_t)b * (NSLICE * 65536) + off] = in4[i];
    }
}

__global__ __launch_bounds__(256, 2)
void step_kernel(const float* __restrict__ state_base,
                 float* __restrict__ out_base,
                 const float* __restrict__ ws,
                 int t) {
    __shared__ half_t tlh[TR * TSTR];   // x fp16 tile, 17680 B

    const int tid = threadIdx.x;
    const int lane = tid & 63, w = tid >> 6;          // 4 waves, 16x64 out each
    const int X0 = blockIdx.x * 64, Y0 = blockIdx.y * 64, b = blockIdx.z;

    const float* __restrict__ in  = state_base + (size_t)(b * NSLICE + (t - 1)) * IMG;
    float* __restrict__ outp      = out_base   + (size_t)(b * NSLICE + t) * IMG;

    // stage 85 x 96 fp32 -> fp16 tile; cols gx in [X0-16, X0+80)
    for (int u = tid; u < TR * 12; u += 256) {
        int r = u / 12, ch = u - r * 12;
        int gr = (Y0 + r - 10) & MASK;
        int gc = X0 + 8 * ch - 16;
        float4 a  = *(const float4*)&in[gr * HW + (gc & MASK)];
        float4 c2 = *(const float4*)&in[gr * HW + ((gc + 4) & MASK)];
        float v[8] = {a.x, a.y, a.z, a.w, c2.x, c2.y, c2.z, c2.w};
        f16x8 hh;
        #pragma unroll
        for (int q = 0; q < 8; ++q) hh[q] = (half_t)v[q];
        *(f16x8*)&tlh[r * TSTR + 8 * ch] = hh;
    }

    // prefetch fp32 residual centers (L2-hot) while staging drains
    const int gy0 = Y0 + 16 * w + (((lane >> 4) & 3) << 2);
    const int gxb = X0 + (lane & 15);
    float4 xv0, xv1, xv2, xv3;
    xv0.x = in[(gy0+0)*HW + gxb];      xv0.y = in[(gy0+1)*HW + gxb];
    xv0.z = in[(gy0+2)*HW + gxb];      xv0.w = in[(gy0+3)*HW + gxb];
    xv1.x = in[(gy0+0)*HW + gxb+16];   xv1.y = in[(gy0+1)*HW + gxb+16];
    xv1.z = in[(gy0+2)*HW + gxb+16];   xv1.w = in[(gy0+3)*HW + gxb+16];
    xv2.x = in[(gy0+0)*HW + gxb+32];   xv2.y = in[(gy0+1)*HW + gxb+32];
    xv2.z = in[(gy0+2)*HW + gxb+32];   xv2.w = in[(gy0+3)*HW + gxb+32];
    xv3.x = in[(gy0+0)*HW + gxb+48];   xv3.y = in[(gy0+1)*HW + gxb+48];
    xv3.z = in[(gy0+2)*HW + gxb+48];   xv3.w = in[(gy0+3)*HW + gxb+48];

    __syncthreads();

    const f16x8* bglob = (const f16x8*)((const unsigned short*)ws + WSB_OFF);
    // A-frag per-lane base: row = 16w + (lane&15) + (lane>>5), col = 8*((lane>>4)&1).
    // Per (p,t): addr = abase + 2p*TSTR + 16t.  (k<16 lanes: row dy; k>=16: dy+1)
    const int abase = (16 * w + (lane & 15) + (lane >> 5)) * TSTR
                    + (((lane >> 4) & 1) << 3);

    f32x4 acc0 = {0.f,0.f,0.f,0.f}, acc1 = acc0, acc2 = acc0, acc3 = acc0;

    // double-buffered A (6 windows) and B (6 frags), static indices only
    f16x8 aX[6], aY[6];
    f16x8 bX[6], bY[6];    // [2u+s]: u window class, s = h/l

    auto LOADA = [&](f16x8 (&A)[6], int p) {
        const half_t* rp = &tlh[abase + 2 * p * TSTR];
        #pragma unroll
        for (int i = 0; i < 6; ++i) A[i] = *(const f16x8*)(rp + 16 * i);
    };
    auto LOADB = [&](f16x8 (&B)[6], int p) {
        const f16x8* nb = bglob + p * 384 + lane;
        #pragma unroll
        for (int i = 0; i < 6; ++i) B[i] = nb[i * 64];
    };
    auto MFMA24 = [&](const f16x8 (&A)[6], const f16x8 (&B)[6]) {
        // h pass: u = 0,1,2 -> B[0],B[2],B[4]
        acc0 = __builtin_amdgcn_mfma_f32_16x16x32_f16(A[0], B[0], acc0, 0,0,0);
        acc1 = __builtin_amdgcn_mfma_f32_16x16x32_f16(A[1], B[0], acc1, 0,0,0);
        acc2 = __builtin_amdgcn_mfma_f32_16x16x32_f16(A[2], B[0], acc2, 0,0,0);
        acc3 = __builtin_amdgcn_mfma_f32_16x16x32_f16(A[3], B[0], acc3, 0,0,0);
        acc0 = __builtin_amdgcn_mfma_f32_16x16x32_f16(A[1], B[2], acc0, 0,0,0);
        acc1 = __builtin_amdgcn_mfma_f32_16x16x32_f16(A[2], B[2], acc1, 0,0,0);
        acc2 = __builtin_amdgcn_mfma_f32_16x16x32_f16(A[3], B[2], acc2, 0,0,0);
        acc3 = __builtin_amdgcn_mfma_f32_16x16x32_f16(A[4], B[2], acc3, 0,0,0);
        acc0 = __builtin_amdgcn_mfma_f32_16x16x32_f16(A[2], B[4], acc0, 0,0,0);
        acc1 = __builtin_amdgcn_mfma_f32_16x16x32_f16(A[3], B[4], acc1, 0,0,0);
        acc2 = __builtin_amdgcn_mfma_f32_16x16x32_f16(A[4], B[4], acc2, 0,0,0);
        acc3 = __builtin_amdgcn_mfma_f32_16x16x32_f16(A[5], B[4], acc3, 0,0,0);
        // l pass: B[1],B[3],B[5]
        acc0 = __builtin_amdgcn_mfma_f32_16x16x32_f16(A[0], B[1], acc0, 0,0,0);
        acc1 = __builtin_amdgcn_mfma_f32_16x16x32_f16(A[1], B[1], acc1, 0,0,0);
        acc2 = __builtin_amdgcn_mfma_f32_16x16x32_f16(A[2], B[1], acc2, 0,0,0);
        acc3 = __builtin_amdgcn_mfma_f32_16x16x32_f16(A[3], B[1], acc3, 0,0,0);
        acc0 = __builtin_amdgcn_mfma_f32_16x16x32_f16(A[1], B[3], acc0, 0,0,0);
        acc1 = __builtin_amdgcn_mfma_f32_16x16x32_f16(A[2], B[3], acc1, 0,0,0);
        acc2 = __builtin_amdgcn_mfma_f32_16x16x32_f16(A[3], B[3], acc2, 0,0,0);
        acc3 = __builtin_amdgcn_mfma_f32_16x16x32_f16(A[4], B[3], acc3, 0,0,0);
        acc0 = __builtin_amdgcn_mfma_f32_16x16x32_f16(A[2], B[5], acc0, 0,0,0);
        acc1 = __builtin_amdgcn_mfma_f32_16x16x32_f16(A[3], B[5], acc1, 0,0,0);
        acc2 = __builtin_amdgcn_mfma_f32_16x16x32_f16(A[4], B[5], acc2, 0,0,0);
        acc3 = __builtin_amdgcn_mfma_f32_16x16x32_f16(A[5], B[5], acc3, 0,0,0);
    };

    // prologue: pair 0 operands in flight
    LOADA(aX, 0);
    LOADB(bX, 0);

    // 11 pairs (dy 0..21; pair 10's second row hits zero weights)
    #define ST(p, AT, AN, BT, BN)                               \
        do {                                                    \
            if ((p) < 10) { LOADA(AN, (p) + 1); LOADB(BN, (p) + 1); } \
            SBAR();                                             \
            MFMA24(AT, BT);                                     \
            SBAR();                                             \
        } while (0)

    ST( 0, aX, aY, bX, bY); ST( 1, aY, aX, bY, bX);
    ST( 2, aX, aY, bX, bY); ST( 3, aY, aX, bY, bX);
    ST( 4, aX, aY, bX, bY); ST( 5, aY, aX, bY, bX);
    ST( 6, aX, aY, bX, bY); ST( 7, aY, aX, bY, bX);
    ST( 8, aX, aY, bX, bY); ST( 9, aY, aX, bY, bX);
    ST(10, aX, aY, bX, bY);
    #undef ST

    // D layout: lane l, reg q -> row = (l>>4)*4 + q, col = l&15 (dtype-indep)
    const float C = ws[0];
    auto EPI = [&](const f32x4& a4v, const float4& xv, int j) {
        int gx = gxb + 16 * j;
        float cv[4] = {xv.x, xv.y, xv.z, xv.w};
        #pragma unroll
        for (int q = 0; q < 4; ++q) {
            int gy = gy0 + q;
            float a  = cv[q] + C * fmaxf(a4v[q], 0.f);
            float e  = __expf(2.f * fabsf(a));        // tanh(|a|) = 1 - 2/(e+1)
            float r  = 1.f - 2.f * __builtin_amdgcn_rcpf(e + 1.f);
            outp[gy * HW + gx] = copysignf(r, a);
        }
    };
    EPI(acc0, xv0, 0); EPI(acc1, xv1, 1); EPI(acc2, xv2, 2); EPI(acc3, xv3, 3);
}

extern "C" void kernel_launch(void* const* d_in, const int* in_sizes, int n_in,
                              void* d_out, int out_size, void* d_ws, size_t ws_size,
                              hipStream_t stream) {
    const float* x  = (const float*)d_in[0];
    const float* w1 = (const float*)d_in[1];
    const float* w2 = (const float*)d_in[2];
    const float* w3 = (const float*)d_in[3];
    float* out = (float*)d_out;
    float* ws  = (float*)d_ws;

    prep_kernel<<<1, 256, 0, stream>>>(w1, w2, w3, ws);
    copy_kernel<<<2048, 256, 0, stream>>>(x, out);

    dim3 grid(8, 8, 8);      // 512 blocks (64x64 out each) = 2/CU
    dim3 block(256);
    for (int t = 1; t <= NSTEP; ++t)
        step_kernel<<<grid, block, 0, stream>>>(out, out, ws, t);
}

// Round 20
// 160.141 us; speedup vs baseline: 2.1375x; 1.3197x over previous
//
#include <hip/hip_runtime.h>
#include <hip/hip_fp16.h>
#include <math.h>

#define HW 512
#define MASK 511
#define IMG (512*512)
#define NSTEP 16
#define NSLICE 17

#define TR 85             // tile rows: [Y0-10, Y0+75); row 84 only feeds zero-weights
#define TSTR 104          // ushort stride/row: 13 granules (odd -> uniform banks)
#define WSB_OFF 32        // ushort offset of B-frag table in ws

typedef _Float16 half_t;
typedef __attribute__((ext_vector_type(8))) _Float16 f16x8;
typedef __attribute__((ext_vector_type(4))) float f32x4;

#define SBAR() __builtin_amdgcn_sched_barrier(0)

// B-frags (2-row Toeplitz, 16x16x32, SINGLE fp16 W): frag f = p*3 + u.
//   p: dy-pair (rows 2p, 2p+1), u: window class (r = 16u).
// lane l, elem j -> k = 8*(l>>4)+j, n = l&15.
//   k<16  -> dy = 2p,   tap d = 16u + k      - n - 6
//   k>=16 -> dy = 2p+1, tap d = 16u + (k-16) - n - 6
// B = rne_fp16(W[dy][d]) if dy<=20 && 0<=d<=20 else 0.  A shares the
// (lane,j)->k map, so any fixed HW k-permutation cancels.
// Numerics anchor: R8 both-bf16 -> 0.529; linear scaling 2^-8 -> 2^-11 gives
// ~0.066 for both-fp16 (R13 x-only measured 0.055, consistent). Margin ~1.3x.
__global__ void prep_kernel(const float* __restrict__ w1,
                            const float* __restrict__ w2,
                            const float* __restrict__ w3,
                            float* __restrict__ ws) {
    int tid = threadIdx.x;
    if (tid == 0) {
        // 1->10->1 MLP on nonneg scalar collapses: C = sum_o w3[o]*max(w2[o],0)
        float c = 0.f;
        for (int o = 0; o < 10; ++o) c += w3[o] * fmaxf(w2[o], 0.f);
        ws[0] = c;
    }
    half_t* wsb = (half_t*)((unsigned short*)ws + WSB_OFF);
    for (int u2 = tid; u2 < 33 * 512; u2 += blockDim.x) {
        int f = u2 >> 9, rem = u2 & 511, l = rem >> 3, j = rem & 7;
        int p = f / 3, rc = f % 3;
        int k = ((l >> 4) << 3) + j, n = l & 15;
        int dy = 2 * p + (k >= 16 ? 1 : 0);
        int d = 16 * rc + (k & 15) - n - 6;
        float wf = (dy <= 20 && d >= 0 && d <= 20) ? w1[dy * 21 + d] : 0.f;
        wsb[u2] = (half_t)wf;              // single rne fp16
    }
}

__global__ void copy_kernel(const float* __restrict__ x, float* __restrict__ out) {
    int i = blockIdx.x * blockDim.x + threadIdx.x;   // float4 index
    if (i < 8 * 65536) {
        const float4* in4 = (const float4*)x;
        float4* out4 = (float4*)out;
        int b = i >> 16;
        int off = i & 65535;
        out4[(size_t)b * (NSLICE * 65536) + off] = in4[i];
    }
}

__global__ __launch_bounds__(256, 2)
void step_kernel(const float* __restrict__ state_base,
                 float* __restrict__ out_base,
                 const float* __restrict__ ws,
                 int t) {
    __shared__ half_t tlh[TR * TSTR];   // x fp16 tile, 17680 B

    const int tid = threadIdx.x;
    const int lane = tid & 63, w = tid >> 6;          // 4 waves, 16x64 out each
    const int X0 = blockIdx.x * 64, Y0 = blockIdx.y * 64, b = blockIdx.z;

    const float* __restrict__ in  = state_base + (size_t)(b * NSLICE + (t - 1)) * IMG;
    float* __restrict__ outp      = out_base   + (size_t)(b * NSLICE + t) * IMG;

    // stage 85 x 96 fp32 -> fp16 tile; cols gx in [X0-16, X0+80)
    for (int u = tid; u < TR * 12; u += 256) {
        int r = u / 12, ch = u - r * 12;
        int gr = (Y0 + r - 10) & MASK;
        int gc = X0 + 8 * ch - 16;
        float4 a  = *(const float4*)&in[gr * HW + (gc & MASK)];
        float4 c2 = *(const float4*)&in[gr * HW + ((gc + 4) & MASK)];
        float v[8] = {a.x, a.y, a.z, a.w, c2.x, c2.y, c2.z, c2.w};
        f16x8 hh;
        #pragma unroll
        for (int q = 0; q < 8; ++q) hh[q] = (half_t)v[q];
        *(f16x8*)&tlh[r * TSTR + 8 * ch] = hh;
    }

    // prefetch fp32 residual centers (L2-hot) while staging drains
    const int gy0 = Y0 + 16 * w + (((lane >> 4) & 3) << 2);
    const int gxb = X0 + (lane & 15);
    float4 xv0, xv1, xv2, xv3;
    xv0.x = in[(gy0+0)*HW + gxb];      xv0.y = in[(gy0+1)*HW + gxb];
    xv0.z = in[(gy0+2)*HW + gxb];      xv0.w = in[(gy0+3)*HW + gxb];
    xv1.x = in[(gy0+0)*HW + gxb+16];   xv1.y = in[(gy0+1)*HW + gxb+16];
    xv1.z = in[(gy0+2)*HW + gxb+16];   xv1.w = in[(gy0+3)*HW + gxb+16];
    xv2.x = in[(gy0+0)*HW + gxb+32];   xv2.y = in[(gy0+1)*HW + gxb+32];
    xv2.z = in[(gy0+2)*HW + gxb+32];   xv2.w = in[(gy0+3)*HW + gxb+32];
    xv3.x = in[(gy0+0)*HW + gxb+48];   xv3.y = in[(gy0+1)*HW + gxb+48];
    xv3.z = in[(gy0+2)*HW + gxb+48];   xv3.w = in[(gy0+3)*HW + gxb+48];

    __syncthreads();

    const f16x8* bglob = (const f16x8*)((const unsigned short*)ws + WSB_OFF);
    // A-frag per-lane base: row = 16w + (lane&15) + (lane>>5), col = 8*((lane>>4)&1).
    const int abase = (16 * w + (lane & 15) + (lane >> 5)) * TSTR
                    + (((lane >> 4) & 1) << 3);

    f32x4 acc0 = {0.f,0.f,0.f,0.f}, acc1 = acc0, acc2 = acc0, acc3 = acc0;

    // double-buffered A (6 windows) and B (3 frags), static indices only
    f16x8 aX[6], aY[6];
    f16x8 bX[3], bY[3];    // [u]: window class

    auto LOADA = [&](f16x8 (&A)[6], int p) {
        const half_t* rp = &tlh[abase + 2 * p * TSTR];
        #pragma unroll
        for (int i = 0; i < 6; ++i) A[i] = *(const f16x8*)(rp + 16 * i);
    };
    auto LOADB = [&](f16x8 (&B)[3], int p) {
        const f16x8* nb = bglob + p * 192 + lane;
        #pragma unroll
        for (int i = 0; i < 3; ++i) B[i] = nb[i * 64];
    };
    auto MFMA12 = [&](const f16x8 (&A)[6], const f16x8 (&B)[3]) {
        acc0 = __builtin_amdgcn_mfma_f32_16x16x32_f16(A[0], B[0], acc0, 0,0,0);
        acc1 = __builtin_amdgcn_mfma_f32_16x16x32_f16(A[1], B[0], acc1, 0,0,0);
        acc2 = __builtin_amdgcn_mfma_f32_16x16x32_f16(A[2], B[0], acc2, 0,0,0);
        acc3 = __builtin_amdgcn_mfma_f32_16x16x32_f16(A[3], B[0], acc3, 0,0,0);
        acc0 = __builtin_amdgcn_mfma_f32_16x16x32_f16(A[1], B[1], acc0, 0,0,0);
        acc1 = __builtin_amdgcn_mfma_f32_16x16x32_f16(A[2], B[1], acc1, 0,0,0);
        acc2 = __builtin_amdgcn_mfma_f32_16x16x32_f16(A[3], B[1], acc2, 0,0,0);
        acc3 = __builtin_amdgcn_mfma_f32_16x16x32_f16(A[4], B[1], acc3, 0,0,0);
        acc0 = __builtin_amdgcn_mfma_f32_16x16x32_f16(A[2], B[2], acc0, 0,0,0);
        acc1 = __builtin_amdgcn_mfma_f32_16x16x32_f16(A[3], B[2], acc1, 0,0,0);
        acc2 = __builtin_amdgcn_mfma_f32_16x16x32_f16(A[4], B[2], acc2, 0,0,0);
        acc3 = __builtin_amdgcn_mfma_f32_16x16x32_f16(A[5], B[2], acc3, 0,0,0);
    };

    // prologue: pair 0 operands in flight
    LOADA(aX, 0);
    LOADB(bX, 0);

    // 11 pairs (dy 0..21; pair 10's second row hits zero weights)
    #define ST(p, AT, AN, BT, BN)                               \
        do {                                                    \
            if ((p) < 10) { LOADA(AN, (p) + 1); LOADB(BN, (p) + 1); } \
            SBAR();                                             \
            MFMA12(AT, BT);                                     \
            SBAR();                                             \
        } while (0)

    ST( 0, aX, aY, bX, bY); ST( 1, aY, aX, bY, bX);
    ST( 2, aX, aY, bX, bY); ST( 3, aY, aX, bY, bX);
    ST( 4, aX, aY, bX, bY); ST( 5, aY, aX, bY, bX);
    ST( 6, aX, aY, bX, bY); ST( 7, aY, aX, bY, bX);
    ST( 8, aX, aY, bX, bY); ST( 9, aY, aX, bY, bX);
    ST(10, aX, aY, bX, bY);
    #undef ST

    // D layout: lane l, reg q -> row = (l>>4)*4 + q, col = l&15 (dtype-indep)
    const float C = ws[0];
    auto EPI = [&](const f32x4& a4v, const float4& xv, int j) {
        int gx = gxb + 16 * j;
        float cv[4] = {xv.x, xv.y, xv.z, xv.w};
        #pragma unroll
        for (int q = 0; q < 4; ++q) {
            int gy = gy0 + q;
            float a  = cv[q] + C * fmaxf(a4v[q], 0.f);
            float e  = __expf(2.f * fabsf(a));        // tanh(|a|) = 1 - 2/(e+1)
            float r  = 1.f - 2.f * __builtin_amdgcn_rcpf(e + 1.f);
            outp[gy * HW + gx] = copysignf(r, a);
        }
    };
    EPI(acc0, xv0, 0); EPI(acc1, xv1, 1); EPI(acc2, xv2, 2); EPI(acc3, xv3, 3);
}

extern "C" void kernel_launch(void* const* d_in, const int* in_sizes, int n_in,
                              void* d_out, int out_size, void* d_ws, size_t ws_size,
                              hipStream_t stream) {
    const float* x  = (const float*)d_in[0];
    const float* w1 = (const float*)d_in[1];
    const float* w2 = (const float*)d_in[2];
    const float* w3 = (const float*)d_in[3];
    float* out = (float*)d_out;
    float* ws  = (float*)d_ws;

    prep_kernel<<<1, 256, 0, stream>>>(w1, w2, w3, ws);
    copy_kernel<<<2048, 256, 0, stream>>>(x, out);

    dim3 grid(8, 8, 8);      // 512 blocks (64x64 out each) = 2/CU
    dim3 block(256);
    for (int t = 1; t <= NSTEP; ++t)
        step_kernel<<<grid, block, 0, stream>>>(out, out, ws, t);
}